// Round 6
// baseline (152.096 us; speedup 1.0000x reference)
//
#include <hip/hip_runtime.h>
#include <hip/hip_bf16.h>

// Problem constants (match reference)
#define BB 8
#define NN 256
#define FF 64      // F_NODE
#define EE 16      // F_EDGE
#define MM 64      // M_MSG
#define G3 192     // 3*F_NODE
#define OUTD 128
#define ROWS (BB*NN)   // 2048
#define MAXD 64        // padded neighbor cap (Binomial(256,0.1): mean 25.6; 64 ~8 sigma)
#define RPB 4          // rows per block in pass kernel

__device__ __forceinline__ float sigmoidf_(float x) {
    return 1.0f / (1.0f + __expf(-x));
}

// ---------------------------------------------------------------------------
// k_prep: one block per row.
//  - edge detect + ballot-scan compaction -> nbr/deg
//  - edot[row][slot][t] = e_{row,j(slot)} @ W_e[:,t]   (pass-invariant!)
//  - h init = nodes; hn0 = nodes @ W_n + b_msg
//  - block 0 zeroes d_out
// ---------------------------------------------------------------------------
__global__ __launch_bounds__(256) void k_prep(
    const float* __restrict__ nodes, const float* __restrict__ edges,
    const float* __restrict__ Wmsg, const float* __restrict__ bmsg,
    int* __restrict__ deg, int* __restrict__ nbr,
    float* __restrict__ h, float* __restrict__ hn,
    float* __restrict__ edot, float* __restrict__ out)
{
    int row = blockIdx.x;
    int tid = threadIdx.x;
    int lane = tid & 63, wv = tid >> 6;
    __shared__ int wcnt[4];
    __shared__ int sdg;
    __shared__ float snode[FF];
    __shared__ float efeat[MAXD][EE];   // 4 KB

    const float4* ep = (const float4*)(edges + (((size_t)row) * NN + tid) * EE);
    float4 a = ep[0], b4 = ep[1], c4 = ep[2], d4 = ep[3];
    float s = a.x+a.y+a.z+a.w + b4.x+b4.y+b4.z+b4.w
            + c4.x+c4.y+c4.z+c4.w + d4.x+d4.y+d4.z+d4.w;
    bool pred = (s != 0.0f);
    unsigned long long m = __ballot(pred);
    if (lane == 0) wcnt[wv] = __popcll(m);
    if (tid < FF) snode[tid] = nodes[(size_t)row * FF + tid];
    __syncthreads();

    int base = 0;
    #pragma unroll
    for (int q = 0; q < 4; ++q) base += (q < wv) ? wcnt[q] : 0;
    int slot = base + __popcll(m & ((1ull << lane) - 1ull));
    if (pred && slot < MAXD) {
        nbr[row * MAXD + slot] = tid;
        // park this edge's 16 features in LDS (already in registers)
        float4* dst = (float4*)&efeat[slot][0];
        dst[0] = a; dst[1] = b4; dst[2] = c4; dst[3] = d4;
    }
    if (tid == 0) {
        int tot = wcnt[0] + wcnt[1] + wcnt[2] + wcnt[3];
        sdg = (tot < MAXD) ? tot : MAXD;
        deg[row] = sdg;
    }
    __syncthreads();

    if (tid < FF) h[row * FF + tid] = snode[tid];
    if (tid < MM) {
        float acc = bmsg[tid];
        #pragma unroll 8
        for (int k = 0; k < FF; ++k) acc += snode[k] * Wmsg[k * MM + tid];
        hn[row * MM + tid] = acc;
    }

    // W_e column 'lane' (rows 64..79 of W_msg) -> registers
    float we[EE];
    #pragma unroll
    for (int k = 0; k < EE; ++k) we[k] = Wmsg[(FF + k) * MM + lane];

    // edot for valid slots: wave wv handles slots wv, wv+4, ...
    int d = sdg;
    float* ed = edot + (size_t)row * MAXD * MM;
    for (int sl = wv; sl < d; sl += 4) {
        float acc = 0.0f;
        #pragma unroll
        for (int k = 0; k < EE; ++k) acc += efeat[sl][k] * we[k];  // LDS broadcast
        ed[sl * MM + lane] = acc;
    }

    if (row == 0) {
        #pragma unroll
        for (int i = 0; i < (BB * OUTD) / 256; ++i) out[i * 256 + tid] = 0.0f;
    }
}

// ---------------------------------------------------------------------------
// k_pass4: 4 rows/block, 1024 threads (16 waves), 512 blocks
//   -> 2 blocks/CU = 32 waves/CU (full occupancy; <=64 VGPR forced).
// msg: 4 waves/row, inner loop = gather(hn) + load(edot) + relu-add.
// GRU gate weights streamed once per block for all 4 rows.
// ---------------------------------------------------------------------------
__global__ __launch_bounds__(1024, 8) void k_pass4(
    const float* __restrict__ Wmsg, const float* __restrict__ bmsg,
    const float* __restrict__ Wi, const float* __restrict__ Wh,
    const float* __restrict__ bi, const float* __restrict__ bh,
    const float* __restrict__ nodes,
    const float* __restrict__ Wg, const float* __restrict__ bg,
    const float* __restrict__ We, const float* __restrict__ be,
    const int* __restrict__ deg, const int* __restrict__ nbr,
    const float* __restrict__ edot,
    const float* __restrict__ hn_in, float* __restrict__ hn_out,
    float* __restrict__ h, float* __restrict__ out, int last)
{
    const int r0   = blockIdx.x * RPB;   // first row of this block
    const int b    = r0 >> 8;            // batch (RPB divides 256 -> uniform)
    const int tid  = threadIdx.x;
    const int w    = tid >> 6;           // wave 0..15
    const int lane = tid & 63;

    __shared__ int   snbr[RPB][MAXD];       // 1 KB
    __shared__ int   sdeg[RPB];
    __shared__ float part[16][MM];          // 4 KB (msg + hnout partials)
    __shared__ float smsg[RPB][MM];         // 1 KB
    __shared__ float sh[RPB][FF];           // h_old, then overwritten with h_new
    __shared__ float sx[RPB][FF];           // pristine nodes (last pass only)
    __shared__ float pg[6][2][RPB][FF];     // 12 KB gate partials
    __shared__ float sg[RPB][OUTD];         // 2 KB
    __shared__ float se[RPB][OUTD];         // 2 KB

    // ---- stage row state (disjoint thread ranges) ----
    if (tid < RPB) sdeg[tid] = deg[r0 + tid];
    if (tid < RPB * MAXD) {
        snbr[tid >> 6][tid & 63] = nbr[(r0 + (tid >> 6)) * MAXD + (tid & 63)];
    } else if (tid < 2 * RPB * MAXD) {
        int x = tid - RPB * MAXD;
        sh[x >> 6][x & 63] = h[(size_t)(r0 + (x >> 6)) * FF + (x & 63)];
    } else if (last && tid < 3 * RPB * MAXD) {
        int x = tid - 2 * RPB * MAXD;
        sx[x >> 6][x & 63] = nodes[(size_t)(r0 + (x >> 6)) * FF + (x & 63)];
    }
    __syncthreads();

    // ---- message aggregation: wave w -> (row w>>2, stride-slot w&3) ----
    {
        int r = w >> 2, sub = w & 3;
        int d = sdeg[r];
        const float* hb = hn_in + (size_t)b * NN * MM;
        const float* ed = edot + (size_t)(r0 + r) * MAXD * MM;
        float acc = 0.0f;
        for (int s = sub; s < d; s += 4) {
            int j = snbr[r][s];
            acc += fmaxf(hb[j * MM + lane] + ed[s * MM + lane], 0.0f);
        }
        part[w][lane] = acc;
    }
    __syncthreads();
    if (tid < RPB * MM) {
        int r = tid >> 6, tt = tid & 63;
        smsg[r][tt] = part[r*4][tt] + part[r*4+1][tt] + part[r*4+2][tt] + part[r*4+3][tt];
    }
    __syncthreads();

    // ---- GRU gates: 12 tasks = (gate g in 0..5, k-half) ----
    // g<3: gi = msg @ Wi ; g>=3: gh = h @ Wh. Weight column loaded once,
    // applied to all 4 rows.
    if (w < 12) {
        int g = w >> 1, kh = w & 1;
        float a0 = 0, a1 = 0, a2 = 0, a3 = 0;
        if (g < 3) {
            for (int k = kh * 32; k < kh * 32 + 32; ++k) {
                float wgt = Wi[k * G3 + g * FF + lane];
                a0 += smsg[0][k] * wgt; a1 += smsg[1][k] * wgt;
                a2 += smsg[2][k] * wgt; a3 += smsg[3][k] * wgt;
            }
        } else {
            int gg = g - 3;
            for (int k = kh * 32; k < kh * 32 + 32; ++k) {
                float wgt = Wh[k * G3 + gg * FF + lane];
                a0 += sh[0][k] * wgt; a1 += sh[1][k] * wgt;
                a2 += sh[2][k] * wgt; a3 += sh[3][k] * wgt;
            }
        }
        pg[g][kh][0][lane] = a0; pg[g][kh][1][lane] = a1;
        pg[g][kh][2][lane] = a2; pg[g][kh][3][lane] = a3;
    }
    __syncthreads();

    // ---- combine: 256 threads = 4 rows x 64 features; overwrite sh=h_new ----
    if (tid < RPB * FF) {
        int r = tid >> 6, tt = tid & 63;
        float ir  = bi[tt]          + pg[0][0][r][tt] + pg[0][1][r][tt];
        float iz  = bi[FF + tt]     + pg[1][0][r][tt] + pg[1][1][r][tt];
        float in_ = bi[2*FF + tt]   + pg[2][0][r][tt] + pg[2][1][r][tt];
        float hr  = bh[tt]          + pg[3][0][r][tt] + pg[3][1][r][tt];
        float hz  = bh[FF + tt]     + pg[4][0][r][tt] + pg[4][1][r][tt];
        float hnn = bh[2*FF + tt]   + pg[5][0][r][tt] + pg[5][1][r][tt];
        float rr = sigmoidf_(ir + hr);
        float zz = sigmoidf_(iz + hz);
        float ng = tanhf(in_ + rr * hnn);
        float hold = sh[r][tt];
        float hnew = (1.0f - zz) * ng + zz * hold;
        if (sdeg[r] == 0) hnew = hold;        // node_mask scatter semantics
        sh[r][tt] = hnew;
        if (!last) h[(size_t)(r0 + r) * FF + tt] = hnew;  // next pass needs it
    }
    __syncthreads();

    if (!last) {
        // hn for next pass: h_new @ W_n + b_msg; 4 waves, each a k-quarter, all rows
        if (w < 4) {
            float a0 = 0, a1 = 0, a2 = 0, a3 = 0;
            #pragma unroll
            for (int kk = 0; kk < 16; ++kk) {
                int k = w * 16 + kk;
                float wgt = Wmsg[k * MM + lane];
                a0 += sh[0][k] * wgt; a1 += sh[1][k] * wgt;
                a2 += sh[2][k] * wgt; a3 += sh[3][k] * wgt;
            }
            part[w*4+0][lane] = a0; part[w*4+1][lane] = a1;
            part[w*4+2][lane] = a2; part[w*4+3][lane] = a3;
        }
        __syncthreads();
        if (tid < RPB * MM) {
            int r = tid >> 6, tt = tid & 63;
            hn_out[(size_t)(r0 + r) * MM + tt] = bmsg[tt]
                + part[0*4+r][tt] + part[1*4+r][tt] + part[2*4+r][tt] + part[3*4+r][tt];
        }
    } else {
        // gated readout: 8 groups of 128 thr = (row r, gate-vs-emb)
        int grp = tid >> 7, o = tid & 127;
        int r = grp >> 1, kind = grp & 1;
        if (kind == 0) {
            float g = bg[o];
            #pragma unroll 4
            for (int k = 0; k < FF; ++k) g += sh[r][k] * Wg[k * OUTD + o];
            #pragma unroll 4
            for (int k = 0; k < FF; ++k) g += sx[r][k] * Wg[(FF + k) * OUTD + o];
            sg[r][o] = g;
        } else {
            float e = be[o];
            #pragma unroll 4
            for (int k = 0; k < FF; ++k) e += sh[r][k] * We[k * OUTD + o];
            se[r][o] = e;
        }
        __syncthreads();
        if (tid < OUTD) {
            float v = 0.0f;
            #pragma unroll
            for (int r2 = 0; r2 < RPB; ++r2)
                v += (sdeg[r2] != 0) ? sigmoidf_(sg[r2][tid]) * se[r2][tid] : 0.0f;
            atomicAdd(&out[b * OUTD + tid], v);
        }
    }
}

// ---------------------------------------------------------------------------
extern "C" void kernel_launch(void* const* d_in, const int* in_sizes, int n_in,
                              void* d_out, int out_size, void* d_ws, size_t ws_size,
                              hipStream_t stream) {
    const float* nodes = (const float*)d_in[0];
    const float* edges = (const float*)d_in[1];
    const float* Wmsg  = (const float*)d_in[2];
    const float* bmsg  = (const float*)d_in[3];
    const float* Wi    = (const float*)d_in[4];
    const float* Wh    = (const float*)d_in[5];
    const float* bi    = (const float*)d_in[6];
    const float* bh    = (const float*)d_in[7];
    const float* Wg    = (const float*)d_in[8];
    const float* bg    = (const float*)d_in[9];
    const float* We    = (const float*)d_in[10];
    const float* be    = (const float*)d_in[11];
    float* out = (float*)d_out;
    char* ws = (char*)d_ws;

    int*   deg  = (int*)ws;                                    // 8 KB
    int*   nbr  = (int*)(ws + 8192);                           // 512 KB
    float* h    = (float*)(ws + 8192 + (size_t)ROWS * MAXD * 4);
    float* hnA  = h    + (size_t)ROWS * FF;                    // 512 KB
    float* hnB  = hnA  + (size_t)ROWS * MM;                    // 512 KB
    float* edot = hnB  + (size_t)ROWS * MM;                    // 2048*64*64*4 = 33.5 MB

    k_prep<<<ROWS, 256, 0, stream>>>(nodes, edges, Wmsg, bmsg, deg, nbr,
                                     h, hnA, edot, out);

    // pass 0: hnA -> hnB ; pass 1: hnB -> hnA ; pass 2: hnA -> readout
    k_pass4<<<ROWS/RPB, 1024, 0, stream>>>(Wmsg, bmsg, Wi, Wh, bi, bh,
                                           nodes, Wg, bg, We, be, deg, nbr, edot,
                                           hnA, hnB, h, out, 0);
    k_pass4<<<ROWS/RPB, 1024, 0, stream>>>(Wmsg, bmsg, Wi, Wh, bi, bh,
                                           nodes, Wg, bg, We, be, deg, nbr, edot,
                                           hnB, hnA, h, out, 0);
    k_pass4<<<ROWS/RPB, 1024, 0, stream>>>(Wmsg, bmsg, Wi, Wh, bi, bh,
                                           nodes, Wg, bg, We, be, deg, nbr, edot,
                                           hnA, hnB, h, out, 1);
}

// Round 7
// 151.313 us; speedup vs baseline: 1.0052x; 1.0052x over previous
//
#include <hip/hip_runtime.h>
#include <hip/hip_bf16.h>

// Problem constants (match reference)
#define BB 8
#define NN 256
#define FF 64      // F_NODE
#define EE 16      // F_EDGE
#define MM 64      // M_MSG
#define G3 192     // 3*F_NODE
#define OUTD 128
#define ROWS (BB*NN)   // 2048
#define MAXD 64        // padded neighbor cap (Binomial(256,0.1): mean 25.6; 64 ~8 sigma)
#define RPB 4          // rows per block in pass kernel (512 thr = 8 waves)

__device__ __forceinline__ float sigmoidf_(float x) {
    return 1.0f / (1.0f + __expf(-x));
}

// ---------------------------------------------------------------------------
// k_prep: one block per row. Edge detect + ballot-scan compaction,
// h init = nodes, hn0 = nodes @ W_n + b_msg. Block 0 zeroes d_out.
// (round-5 proven version; no edot materialization)
// ---------------------------------------------------------------------------
__global__ __launch_bounds__(256) void k_prep(
    const float* __restrict__ nodes, const float* __restrict__ edges,
    const float* __restrict__ Wmsg, const float* __restrict__ bmsg,
    int* __restrict__ deg, int* __restrict__ nbr,
    float* __restrict__ h, float* __restrict__ hn, float* __restrict__ out)
{
    int row = blockIdx.x;
    int tid = threadIdx.x;
    int lane = tid & 63, wv = tid >> 6;
    __shared__ int wcnt[4];
    __shared__ float snode[FF];

    const float4* ep = (const float4*)(edges + (((size_t)row) * NN + tid) * EE);
    float4 a = ep[0], b4 = ep[1], c4 = ep[2], d4 = ep[3];
    float s = a.x+a.y+a.z+a.w + b4.x+b4.y+b4.z+b4.w
            + c4.x+c4.y+c4.z+c4.w + d4.x+d4.y+d4.z+d4.w;
    bool pred = (s != 0.0f);
    unsigned long long m = __ballot(pred);
    if (lane == 0) wcnt[wv] = __popcll(m);
    if (tid < FF) snode[tid] = nodes[(size_t)row * FF + tid];
    __syncthreads();

    int base = 0;
    #pragma unroll
    for (int q = 0; q < 4; ++q) base += (q < wv) ? wcnt[q] : 0;
    int slot = base + __popcll(m & ((1ull << lane) - 1ull));
    if (pred && slot < MAXD) nbr[row * MAXD + slot] = tid;

    if (tid == 0) {
        int tot = wcnt[0] + wcnt[1] + wcnt[2] + wcnt[3];
        deg[row] = (tot < MAXD) ? tot : MAXD;
    }
    if (tid < FF) h[row * FF + tid] = snode[tid];
    if (tid < MM) {
        float acc = bmsg[tid];
        #pragma unroll 8
        for (int k = 0; k < FF; ++k) acc += snode[k] * Wmsg[k * MM + tid];
        hn[row * MM + tid] = acc;
    }
    if (row == 0) {
        #pragma unroll
        for (int i = 0; i < (BB * OUTD) / 256; ++i) out[i * 256 + tid] = 0.0f;
    }
}

// ---------------------------------------------------------------------------
// k_pass4: 4 rows/block, 512 threads (8 waves), 512 blocks
//   -> 4 blocks/CU = 32 waves/CU (full occupancy; launch_bounds(512,8)).
// Gate weight columns loaded ONCE per block, applied to all 4 rows
// (halves Wi/Wh L2 traffic vs 2 rows/block). e.W_e recomputed from LDS
// (R6 lesson: materializing it through HBM costs more than the VALU).
// ---------------------------------------------------------------------------
__global__ __launch_bounds__(512, 8) void k_pass4(
    const float* __restrict__ edges,
    const float* __restrict__ Wmsg, const float* __restrict__ bmsg,
    const float* __restrict__ Wi, const float* __restrict__ Wh,
    const float* __restrict__ bi, const float* __restrict__ bh,
    const float* __restrict__ nodes,
    const float* __restrict__ Wg, const float* __restrict__ bg,
    const float* __restrict__ We, const float* __restrict__ be,
    const int* __restrict__ deg, const int* __restrict__ nbr,
    const float* __restrict__ hn_in, float* __restrict__ hn_out,
    float* __restrict__ h, float* __restrict__ out, int last)
{
    const int r0   = blockIdx.x * RPB;   // first row of this block
    const int b    = r0 >> 8;            // batch (RPB divides 256 -> uniform)
    const int tid  = threadIdx.x;
    const int w    = tid >> 6;           // wave 0..7
    const int lane = tid & 63;

    __shared__ int   snbr[RPB][MAXD];       // 1 KB
    __shared__ int   sdeg[RPB];
    __shared__ float efeat[RPB][MAXD][EE];  // 16 KB
    __shared__ float part[8][MM];           // 2 KB (msg + hnout partials)
    __shared__ float smsg[RPB][MM];         // 1 KB
    __shared__ float sh[RPB][FF];           // h_old -> h_new
    __shared__ float sx[RPB][FF];           // pristine nodes (last pass only)
    __shared__ float pg[6][RPB][FF];        // 6 KB gate results
    __shared__ float sg[RPB][OUTD];         // 2 KB
    __shared__ float se[RPB][OUTD];         // 2 KB

    // ---- stage row state (disjoint thread ranges) ----
    if (tid < RPB) sdeg[tid] = deg[r0 + tid];
    if (tid < RPB * MAXD) {                 // 256 threads: neighbor lists
        snbr[tid >> 6][tid & 63] = nbr[(r0 + (tid >> 6)) * MAXD + (tid & 63)];
        if (last) {
            int r = tid >> 6, k = tid & 63;
            sx[r][k] = nodes[(size_t)(r0 + r) * FF + k];
        }
    } else {                                // 256 threads: h state
        int x = tid - RPB * MAXD;
        sh[x >> 6][x & 63] = h[(size_t)(r0 + (x >> 6)) * FF + (x & 63)];
    }

    // W_e column 'lane' (rows 64..79 of W_msg) -> registers
    float we[EE];
    #pragma unroll
    for (int k = 0; k < EE; ++k) we[k] = Wmsg[(FF + k) * MM + lane];
    __syncthreads();

    // ---- gather edge features into LDS (float4-vectorized) ----
    #pragma unroll
    for (int r = 0; r < RPB; ++r) {
        int cnt4 = sdeg[r] * 4;             // 4 float4 per edge slot
        for (int i = tid; i < cnt4; i += 512) {
            int slot = i >> 2, q = i & 3;
            const float4* src =
                (const float4*)(edges + (((size_t)(r0 + r)) * NN + snbr[r][slot]) * EE);
            ((float4*)&efeat[r][slot][0])[q] = src[q];
        }
    }
    __syncthreads();

    // ---- message aggregation: wave w -> (row w>>1, stride-slot w&1) ----
    {
        int r = w >> 1, sub = w & 1;
        int d = sdeg[r];
        const float* hb = hn_in + (size_t)b * NN * MM;
        float acc = 0.0f;
        for (int s = sub; s < d; s += 2) {
            int j = snbr[r][s];
            float term = hb[j * MM + lane];
            #pragma unroll
            for (int k = 0; k < EE; ++k) term += efeat[r][s][k] * we[k];
            acc += fmaxf(term, 0.0f);
        }
        part[w][lane] = acc;
    }
    __syncthreads();
    if (tid < RPB * MM) {
        int r = tid >> 6, tt = tid & 63;
        smsg[r][tt] = part[2*r][tt] + part[2*r+1][tt];
    }
    __syncthreads();

    // ---- GRU gates: wave g<3 -> gi gate g; 3<=g<6 -> gh gate g-3 ----
    // weight column loaded once, applied to all 4 rows
    if (w < 3) {
        float a0 = bi[w * FF + lane], a1 = a0, a2 = a0, a3 = a0;
        #pragma unroll 4
        for (int k = 0; k < FF; ++k) {
            float wgt = Wi[k * G3 + w * FF + lane];
            a0 += smsg[0][k] * wgt; a1 += smsg[1][k] * wgt;
            a2 += smsg[2][k] * wgt; a3 += smsg[3][k] * wgt;
        }
        pg[w][0][lane] = a0; pg[w][1][lane] = a1;
        pg[w][2][lane] = a2; pg[w][3][lane] = a3;
    } else if (w < 6) {
        int g = w - 3;
        float a0 = bh[g * FF + lane], a1 = a0, a2 = a0, a3 = a0;
        #pragma unroll 4
        for (int k = 0; k < FF; ++k) {
            float wgt = Wh[k * G3 + g * FF + lane];
            a0 += sh[0][k] * wgt; a1 += sh[1][k] * wgt;
            a2 += sh[2][k] * wgt; a3 += sh[3][k] * wgt;
        }
        pg[3 + g][0][lane] = a0; pg[3 + g][1][lane] = a1;
        pg[3 + g][2][lane] = a2; pg[3 + g][3][lane] = a3;
    }
    __syncthreads();

    // ---- combine: 256 threads = 4 rows x 64 features; sh <- h_new ----
    if (tid < RPB * FF) {
        int r = tid >> 6, tt = tid & 63;
        float rr = sigmoidf_(pg[0][r][tt] + pg[3][r][tt]);
        float zz = sigmoidf_(pg[1][r][tt] + pg[4][r][tt]);
        float ng = tanhf(pg[2][r][tt] + rr * pg[5][r][tt]);
        float hold = sh[r][tt];
        float hnew = (1.0f - zz) * ng + zz * hold;
        if (sdeg[r] == 0) hnew = hold;        // node_mask scatter semantics
        sh[r][tt] = hnew;
        if (!last) h[(size_t)(r0 + r) * FF + tt] = hnew;
    }
    __syncthreads();

    if (!last) {
        // hn for next pass: h_new @ W_n + b_msg; 8 waves = 4 rows x 2 k-halves
        {
            int r = w >> 1, kh = w & 1;
            float p = 0.0f;
            #pragma unroll
            for (int kk = 0; kk < 32; ++kk) {
                int k = kh * 32 + kk;
                p += sh[r][k] * Wmsg[k * MM + lane];
            }
            part[w][lane] = p;
        }
        __syncthreads();
        if (tid < RPB * MM) {
            int r = tid >> 6, tt = tid & 63;
            hn_out[(size_t)(r0 + r) * MM + tt] = bmsg[tt]
                + part[2*r][tt] + part[2*r+1][tt];
        }
    } else {
        // gated readout: 4 groups of 128 thr, group = row; each computes g and e
        int r = tid >> 7, o = tid & 127;
        float g = bg[o], e = be[o];
        #pragma unroll 4
        for (int k = 0; k < FF; ++k) {
            float hk = sh[r][k];
            g += hk * Wg[k * OUTD + o];
            e += hk * We[k * OUTD + o];
        }
        #pragma unroll 4
        for (int k = 0; k < FF; ++k) g += sx[r][k] * Wg[(FF + k) * OUTD + o];
        sg[r][o] = g; se[r][o] = e;
        __syncthreads();
        if (tid < OUTD) {
            float v = 0.0f;
            #pragma unroll
            for (int r2 = 0; r2 < RPB; ++r2)
                v += (sdeg[r2] != 0) ? sigmoidf_(sg[r2][tid]) * se[r2][tid] : 0.0f;
            atomicAdd(&out[b * OUTD + tid], v);
        }
    }
}

// ---------------------------------------------------------------------------
extern "C" void kernel_launch(void* const* d_in, const int* in_sizes, int n_in,
                              void* d_out, int out_size, void* d_ws, size_t ws_size,
                              hipStream_t stream) {
    const float* nodes = (const float*)d_in[0];
    const float* edges = (const float*)d_in[1];
    const float* Wmsg  = (const float*)d_in[2];
    const float* bmsg  = (const float*)d_in[3];
    const float* Wi    = (const float*)d_in[4];
    const float* Wh    = (const float*)d_in[5];
    const float* bi    = (const float*)d_in[6];
    const float* bh    = (const float*)d_in[7];
    const float* Wg    = (const float*)d_in[8];
    const float* bg    = (const float*)d_in[9];
    const float* We    = (const float*)d_in[10];
    const float* be    = (const float*)d_in[11];
    float* out = (float*)d_out;
    char* ws = (char*)d_ws;

    int*   deg  = (int*)ws;                                    // 8 KB
    int*   nbr  = (int*)(ws + 8192);                           // 512 KB
    float* h    = (float*)(ws + 8192 + (size_t)ROWS * MAXD * 4);
    float* hnA  = h   + (size_t)ROWS * FF;                     // 512 KB
    float* hnB  = hnA + (size_t)ROWS * MM;                     // 512 KB

    k_prep<<<ROWS, 256, 0, stream>>>(nodes, edges, Wmsg, bmsg, deg, nbr, h, hnA, out);

    // pass 0: hnA -> hnB ; pass 1: hnB -> hnA ; pass 2: hnA -> readout
    k_pass4<<<ROWS/RPB, 512, 0, stream>>>(edges, Wmsg, bmsg, Wi, Wh, bi, bh,
                                          nodes, Wg, bg, We, be, deg, nbr,
                                          hnA, hnB, h, out, 0);
    k_pass4<<<ROWS/RPB, 512, 0, stream>>>(edges, Wmsg, bmsg, Wi, Wh, bi, bh,
                                          nodes, Wg, bg, We, be, deg, nbr,
                                          hnB, hnA, h, out, 0);
    k_pass4<<<ROWS/RPB, 512, 0, stream>>>(edges, Wmsg, bmsg, Wi, Wh, bi, bh,
                                          nodes, Wg, bg, We, be, deg, nbr,
                                          hnA, hnB, h, out, 1);
}

// Round 8
// 146.518 us; speedup vs baseline: 1.0381x; 1.0327x over previous
//
#include <hip/hip_runtime.h>
#include <hip/hip_bf16.h>

// Problem constants (match reference)
#define BB 8
#define NN 256
#define FF 64      // F_NODE
#define EE 16      // F_EDGE
#define MM 64      // M_MSG
#define G3 192     // 3*F_NODE
#define OUTD 128
#define ROWS (BB*NN)   // 2048
#define MAXD 64        // padded neighbor cap (Binomial(256,0.1): mean 25.6; 64 ~8 sigma)
#define RPB 4          // rows per block (1024 thr = 16 waves -> 4 msg-waves/row)

__device__ __forceinline__ float sigmoidf_(float x) {
    return 1.0f / (1.0f + __expf(-x));
}

// ---------------------------------------------------------------------------
// k_prep: one block per row. Edge detect + ballot-scan compaction,
// h init = nodes, hn0 = nodes @ W_n + b_msg. Block 0 zeroes d_out.
// (proven R5 version)
// ---------------------------------------------------------------------------
__global__ __launch_bounds__(256) void k_prep(
    const float* __restrict__ nodes, const float* __restrict__ edges,
    const float* __restrict__ Wmsg, const float* __restrict__ bmsg,
    int* __restrict__ deg, int* __restrict__ nbr,
    float* __restrict__ h, float* __restrict__ hn, float* __restrict__ out)
{
    int row = blockIdx.x;
    int tid = threadIdx.x;
    int lane = tid & 63, wv = tid >> 6;
    __shared__ int wcnt[4];
    __shared__ float snode[FF];

    const float4* ep = (const float4*)(edges + (((size_t)row) * NN + tid) * EE);
    float4 a = ep[0], b4 = ep[1], c4 = ep[2], d4 = ep[3];
    float s = a.x+a.y+a.z+a.w + b4.x+b4.y+b4.z+b4.w
            + c4.x+c4.y+c4.z+c4.w + d4.x+d4.y+d4.z+d4.w;
    bool pred = (s != 0.0f);
    unsigned long long m = __ballot(pred);
    if (lane == 0) wcnt[wv] = __popcll(m);
    if (tid < FF) snode[tid] = nodes[(size_t)row * FF + tid];
    __syncthreads();

    int base = 0;
    #pragma unroll
    for (int q = 0; q < 4; ++q) base += (q < wv) ? wcnt[q] : 0;
    int slot = base + __popcll(m & ((1ull << lane) - 1ull));
    if (pred && slot < MAXD) nbr[row * MAXD + slot] = tid;

    if (tid == 0) {
        int tot = wcnt[0] + wcnt[1] + wcnt[2] + wcnt[3];
        deg[row] = (tot < MAXD) ? tot : MAXD;
    }
    if (tid < FF) h[row * FF + tid] = snode[tid];
    if (tid < MM) {
        float acc = bmsg[tid];
        #pragma unroll 8
        for (int k = 0; k < FF; ++k) acc += snode[k] * Wmsg[k * MM + tid];
        hn[row * MM + tid] = acc;
    }
    if (row == 0) {
        #pragma unroll
        for (int i = 0; i < (BB * OUTD) / 256; ++i) out[i * 256 + tid] = 0.0f;
    }
}

// ---------------------------------------------------------------------------
// k_pass4: 4 rows/block, 1024 threads (16 waves), 512 blocks
//   -> 2 blocks/CU = 32 waves/CU (full occupancy; launch_bounds(1024,8)).
// msg: 16 waves = 4 waves/row (R5-parity parallelism).
// gates: 12 waves = 6 gates x 2 k-halves; weight column loaded once,
//        applied to all 4 rows (halves Wi/Wh L2 traffic vs 2-row blocks).
// e.W_e recomputed from LDS efeat (R6 lesson: don't materialize via HBM).
// ---------------------------------------------------------------------------
__global__ __launch_bounds__(1024, 8) void k_pass4(
    const float* __restrict__ edges,
    const float* __restrict__ Wmsg, const float* __restrict__ bmsg,
    const float* __restrict__ Wi, const float* __restrict__ Wh,
    const float* __restrict__ bi, const float* __restrict__ bh,
    const float* __restrict__ nodes,
    const float* __restrict__ Wg, const float* __restrict__ bg,
    const float* __restrict__ We, const float* __restrict__ be,
    const int* __restrict__ deg, const int* __restrict__ nbr,
    const float* __restrict__ hn_in, float* __restrict__ hn_out,
    float* __restrict__ h, float* __restrict__ out, int last)
{
    const int r0   = blockIdx.x * RPB;   // first row of this block
    const int b    = r0 >> 8;            // batch (RPB divides 256 -> uniform)
    const int tid  = threadIdx.x;
    const int w    = tid >> 6;           // wave 0..15
    const int lane = tid & 63;

    __shared__ int   snbr[RPB][MAXD];       // 1 KB
    __shared__ int   sdeg[RPB];
    __shared__ float efeat[RPB][MAXD][EE];  // 16 KB
    __shared__ float part[16][MM];          // 4 KB (msg + hnout partials)
    __shared__ float smsg[RPB][MM];         // 1 KB
    __shared__ float sh[RPB][FF];           // h_old -> h_new
    __shared__ float sx[RPB][FF];           // pristine nodes (last pass only)
    __shared__ float pg[6][2][RPB][FF];     // 12 KB gate partials
    __shared__ float sg[RPB][OUTD];         // 2 KB
    __shared__ float se[RPB][OUTD];         // 2 KB

    // ---- stage row state (disjoint thread ranges) ----
    if (tid < RPB) sdeg[tid] = deg[r0 + tid];
    if (tid < RPB * MAXD) {                 // 256 thr: neighbor lists
        snbr[tid >> 6][tid & 63] = nbr[(r0 + (tid >> 6)) * MAXD + (tid & 63)];
    } else if (tid < 2 * RPB * MAXD) {      // 256 thr: h state
        int x = tid - RPB * MAXD;
        sh[x >> 6][x & 63] = h[(size_t)(r0 + (x >> 6)) * FF + (x & 63)];
    } else if (last && tid < 3 * RPB * MAXD) { // 256 thr: pristine nodes
        int x = tid - 2 * RPB * MAXD;
        sx[x >> 6][x & 63] = nodes[(size_t)(r0 + (x >> 6)) * FF + (x & 63)];
    }

    // W_e column 'lane' (rows 64..79 of W_msg) -> registers
    float we[EE];
    #pragma unroll
    for (int k = 0; k < EE; ++k) we[k] = Wmsg[(FF + k) * MM + lane];
    __syncthreads();

    // ---- gather edge features into LDS (float4-vectorized) ----
    #pragma unroll
    for (int r = 0; r < RPB; ++r) {
        int cnt4 = sdeg[r] * 4;             // 4 float4 per edge slot
        for (int i = tid; i < cnt4; i += 1024) {
            int slot = i >> 2, q = i & 3;
            const float4* src =
                (const float4*)(edges + (((size_t)(r0 + r)) * NN + snbr[r][slot]) * EE);
            ((float4*)&efeat[r][slot][0])[q] = src[q];
        }
    }
    __syncthreads();

    // ---- message aggregation: wave w -> (row w>>2, stride-slot w&3) ----
    {
        int r = w >> 2, sub = w & 3;
        int d = sdeg[r];
        const float* hb = hn_in + (size_t)b * NN * MM;
        float acc = 0.0f;
        for (int s = sub; s < d; s += 4) {
            int j = snbr[r][s];
            float term = hb[j * MM + lane];
            #pragma unroll
            for (int k = 0; k < EE; ++k) term += efeat[r][s][k] * we[k];
            acc += fmaxf(term, 0.0f);
        }
        part[w][lane] = acc;
    }
    __syncthreads();
    if (tid < RPB * MM) {
        int r = tid >> 6, tt = tid & 63;
        smsg[r][tt] = part[4*r][tt] + part[4*r+1][tt] + part[4*r+2][tt] + part[4*r+3][tt];
    }
    __syncthreads();

    // ---- GRU gates: 12 waves = (gate g 0..5, k-half); 4-row weight reuse ----
    if (w < 12) {
        int g = w >> 1, kh = w & 1;
        float a0 = 0, a1 = 0, a2 = 0, a3 = 0;
        if (g < 3) {
            for (int k = kh * 32; k < kh * 32 + 32; ++k) {
                float wgt = Wi[k * G3 + g * FF + lane];
                a0 += smsg[0][k] * wgt; a1 += smsg[1][k] * wgt;
                a2 += smsg[2][k] * wgt; a3 += smsg[3][k] * wgt;
            }
        } else {
            int gg = g - 3;
            for (int k = kh * 32; k < kh * 32 + 32; ++k) {
                float wgt = Wh[k * G3 + gg * FF + lane];
                a0 += sh[0][k] * wgt; a1 += sh[1][k] * wgt;
                a2 += sh[2][k] * wgt; a3 += sh[3][k] * wgt;
            }
        }
        pg[g][kh][0][lane] = a0; pg[g][kh][1][lane] = a1;
        pg[g][kh][2][lane] = a2; pg[g][kh][3][lane] = a3;
    }
    __syncthreads();

    // ---- combine: 256 threads = 4 rows x 64 features; sh <- h_new ----
    if (tid < RPB * FF) {
        int r = tid >> 6, tt = tid & 63;
        float ir  = bi[tt]        + pg[0][0][r][tt] + pg[0][1][r][tt];
        float iz  = bi[FF + tt]   + pg[1][0][r][tt] + pg[1][1][r][tt];
        float in_ = bi[2*FF + tt] + pg[2][0][r][tt] + pg[2][1][r][tt];
        float hr  = bh[tt]        + pg[3][0][r][tt] + pg[3][1][r][tt];
        float hz  = bh[FF + tt]   + pg[4][0][r][tt] + pg[4][1][r][tt];
        float hnn = bh[2*FF + tt] + pg[5][0][r][tt] + pg[5][1][r][tt];
        float rr = sigmoidf_(ir + hr);
        float zz = sigmoidf_(iz + hz);
        float ng = tanhf(in_ + rr * hnn);
        float hold = sh[r][tt];
        float hnew = (1.0f - zz) * ng + zz * hold;
        if (sdeg[r] == 0) hnew = hold;        // node_mask scatter semantics
        sh[r][tt] = hnew;
        if (!last) h[(size_t)(r0 + r) * FF + tt] = hnew;
    }
    __syncthreads();

    if (!last) {
        // hn for next pass: h_new @ W_n + b_msg; 8 waves = 4 rows x 2 k-halves
        if (w < 8) {
            int r = w >> 1, kh = w & 1;
            float p = 0.0f;
            #pragma unroll
            for (int kk = 0; kk < 32; ++kk) {
                int k = kh * 32 + kk;
                p += sh[r][k] * Wmsg[k * MM + lane];
            }
            part[w][lane] = p;
        }
        __syncthreads();
        if (tid < RPB * MM) {
            int r = tid >> 6, tt = tid & 63;
            hn_out[(size_t)(r0 + r) * MM + tt] = bmsg[tt]
                + part[2*r][tt] + part[2*r+1][tt];
        }
    } else {
        // gated readout: 8 groups of 128 thr = (row r, gate-vs-emb)
        int grp = tid >> 7, o = tid & 127;
        int r = grp >> 1, kind = grp & 1;
        if (kind == 0) {
            float g = bg[o];
            #pragma unroll 4
            for (int k = 0; k < FF; ++k) g += sh[r][k] * Wg[k * OUTD + o];
            #pragma unroll 4
            for (int k = 0; k < FF; ++k) g += sx[r][k] * Wg[(FF + k) * OUTD + o];
            sg[r][o] = g;
        } else {
            float e = be[o];
            #pragma unroll 4
            for (int k = 0; k < FF; ++k) e += sh[r][k] * We[k * OUTD + o];
            se[r][o] = e;
        }
        __syncthreads();
        if (tid < OUTD) {
            float v = 0.0f;
            #pragma unroll
            for (int r2 = 0; r2 < RPB; ++r2)
                v += (sdeg[r2] != 0) ? sigmoidf_(sg[r2][tid]) * se[r2][tid] : 0.0f;
            atomicAdd(&out[b * OUTD + tid], v);
        }
    }
}

// ---------------------------------------------------------------------------
extern "C" void kernel_launch(void* const* d_in, const int* in_sizes, int n_in,
                              void* d_out, int out_size, void* d_ws, size_t ws_size,
                              hipStream_t stream) {
    const float* nodes = (const float*)d_in[0];
    const float* edges = (const float*)d_in[1];
    const float* Wmsg  = (const float*)d_in[2];
    const float* bmsg  = (const float*)d_in[3];
    const float* Wi    = (const float*)d_in[4];
    const float* Wh    = (const float*)d_in[5];
    const float* bi    = (const float*)d_in[6];
    const float* bh    = (const float*)d_in[7];
    const float* Wg    = (const float*)d_in[8];
    const float* bg    = (const float*)d_in[9];
    const float* We    = (const float*)d_in[10];
    const float* be    = (const float*)d_in[11];
    float* out = (float*)d_out;
    char* ws = (char*)d_ws;

    int*   deg  = (int*)ws;                                    // 8 KB
    int*   nbr  = (int*)(ws + 8192);                           // 512 KB
    float* h    = (float*)(ws + 8192 + (size_t)ROWS * MAXD * 4);
    float* hnA  = h   + (size_t)ROWS * FF;                     // 512 KB
    float* hnB  = hnA + (size_t)ROWS * MM;                     // 512 KB

    k_prep<<<ROWS, 256, 0, stream>>>(nodes, edges, Wmsg, bmsg, deg, nbr, h, hnA, out);

    // pass 0: hnA -> hnB ; pass 1: hnB -> hnA ; pass 2: hnA -> readout
    k_pass4<<<ROWS/RPB, 1024, 0, stream>>>(edges, Wmsg, bmsg, Wi, Wh, bi, bh,
                                           nodes, Wg, bg, We, be, deg, nbr,
                                           hnA, hnB, h, out, 0);
    k_pass4<<<ROWS/RPB, 1024, 0, stream>>>(edges, Wmsg, bmsg, Wi, Wh, bi, bh,
                                           nodes, Wg, bg, We, be, deg, nbr,
                                           hnB, hnA, h, out, 0);
    k_pass4<<<ROWS/RPB, 1024, 0, stream>>>(edges, Wmsg, bmsg, Wi, Wh, bi, bh,
                                           nodes, Wg, bg, We, be, deg, nbr,
                                           hnA, hnB, h, out, 1);
}

// Round 9
// 145.161 us; speedup vs baseline: 1.0478x; 1.0094x over previous
//
#include <hip/hip_runtime.h>
#include <hip/hip_bf16.h>

// Problem constants (match reference)
#define BB 8
#define NN 256
#define FF 64      // F_NODE
#define EE 16      // F_EDGE
#define MM 64      // M_MSG
#define G3 192     // 3*F_NODE
#define OUTD 128
#define ROWS (BB*NN)   // 2048
#define MAXD 64        // padded neighbor cap (Binomial(256,0.1): mean 25.6; 64 ~8 sigma)

// Tile-shape sweep (measured, total bench us): 1row/256t=156.2, 2row/512t=144.5,
// 4row/512t=151.3, 4row/1024t=146.5, 4row/1024t+edot=152.1, coop-1-dispatch=334.6.
// 2 rows/block @ 512 thr is the empirical optimum: msg keeps 4 waves/row (short
// serial gather chains) and the gate phase is latency-bound, not L2-BW-bound,
// so further weight-reuse doesn't pay.

__device__ __forceinline__ float sigmoidf_(float x) {
    return 1.0f / (1.0f + __expf(-x));
}

// ---------------------------------------------------------------------------
// k_prep: one block per row. Edge detect + ballot-scan compaction,
// h init = nodes, hn0 = nodes @ W_n + b_msg. Block 0 zeroes d_out.
// ---------------------------------------------------------------------------
__global__ __launch_bounds__(256) void k_prep(
    const float* __restrict__ nodes, const float* __restrict__ edges,
    const float* __restrict__ Wmsg, const float* __restrict__ bmsg,
    int* __restrict__ deg, int* __restrict__ nbr,
    float* __restrict__ h, float* __restrict__ hn, float* __restrict__ out)
{
    int row = blockIdx.x;
    int tid = threadIdx.x;
    int lane = tid & 63, wv = tid >> 6;
    __shared__ int wcnt[4];
    __shared__ float snode[FF];

    const float4* ep = (const float4*)(edges + (((size_t)row) * NN + tid) * EE);
    float4 a = ep[0], b4 = ep[1], c4 = ep[2], d4 = ep[3];
    float s = a.x+a.y+a.z+a.w + b4.x+b4.y+b4.z+b4.w
            + c4.x+c4.y+c4.z+c4.w + d4.x+d4.y+d4.z+d4.w;
    bool pred = (s != 0.0f);
    unsigned long long m = __ballot(pred);
    if (lane == 0) wcnt[wv] = __popcll(m);
    if (tid < FF) snode[tid] = nodes[(size_t)row * FF + tid];
    __syncthreads();

    int base = 0;
    #pragma unroll
    for (int q = 0; q < 4; ++q) base += (q < wv) ? wcnt[q] : 0;
    int slot = base + __popcll(m & ((1ull << lane) - 1ull));
    if (pred && slot < MAXD) nbr[row * MAXD + slot] = tid;

    if (tid == 0) {
        int tot = wcnt[0] + wcnt[1] + wcnt[2] + wcnt[3];
        deg[row] = (tot < MAXD) ? tot : MAXD;
    }
    if (tid < FF) h[row * FF + tid] = snode[tid];
    if (tid < MM) {
        float acc = bmsg[tid];
        #pragma unroll 8
        for (int k = 0; k < FF; ++k) acc += snode[k] * Wmsg[k * MM + tid];
        hn[row * MM + tid] = acc;
    }
    // zero output accumulator (stream ordering: readout atomics run later)
    if (row == 0) {
        #pragma unroll
        for (int i = 0; i < (BB * OUTD) / 256; ++i) out[i * 256 + tid] = 0.0f;
    }
}

// ---------------------------------------------------------------------------
// k_pass2: 2 rows per block, 512 threads (8 waves), 1024 blocks
//          -> 4 blocks/CU = 32 waves/CU (full occupancy).
// Gate weight columns loaded once per block, applied to both rows.
// msg: 4 waves per row (short serial gather chains — the winning config).
// efeat gather float4-vectorized (only delta vs the 144.5 us R5 kernel).
// ---------------------------------------------------------------------------
__global__ __launch_bounds__(512, 8) void k_pass2(
    const float* __restrict__ edges,
    const float* __restrict__ Wmsg, const float* __restrict__ bmsg,
    const float* __restrict__ Wi, const float* __restrict__ Wh,
    const float* __restrict__ bi, const float* __restrict__ bh,
    const float* __restrict__ nodes,
    const float* __restrict__ Wg, const float* __restrict__ bg,
    const float* __restrict__ We, const float* __restrict__ be,
    const int* __restrict__ deg, const int* __restrict__ nbr,
    const float* __restrict__ hn_in, float* __restrict__ hn_out,
    float* __restrict__ h, float* __restrict__ out, int last)
{
    const int r0  = blockIdx.x * 2;      // first row of this block
    const int b   = r0 >> 8;             // batch (2 divides 256 -> uniform)
    const int tid = threadIdx.x;
    const int w   = tid >> 6;            // wave 0..7
    const int lane = tid & 63;

    __shared__ int   snbr[2][MAXD];
    __shared__ int   sdeg[2];
    __shared__ float efeat[2][MAXD][EE];   // 8 KB
    __shared__ float part[8][MM];          // 2 KB
    __shared__ float smsg[2][MM];
    __shared__ float shold[2][FF];
    __shared__ float sx[2][FF];
    __shared__ float gI[2][3][FF], gH[2][3][FF];
    __shared__ float shnew[2][FF];
    __shared__ float sg[2][OUTD], se[2][OUTD];

    // ---- stage row state ----
    if (tid < 2) sdeg[tid] = deg[r0 + tid];
    if (tid < 2 * MAXD) {
        int r = tid >> 6;
        snbr[r][tid & 63] = nbr[(r0 + r) * MAXD + (tid & 63)];
    }
    if (tid < 2 * FF) {
        int r = tid >> 6;
        shold[r][tid & 63] = h[(size_t)(r0 + r) * FF + (tid & 63)];
    }
    if (last && tid >= 2 * FF && tid < 4 * FF) {
        int r = (tid >> 6) & 1;
        sx[r][tid & 63] = nodes[(size_t)(r0 + r) * FF + (tid & 63)];
    }

    // W_e column (rows 64..79 of W_msg) -> registers
    float we[EE];
    #pragma unroll
    for (int k = 0; k < EE; ++k) we[k] = Wmsg[(FF + k) * MM + lane];
    __syncthreads();

    // ---- gather edge features into LDS (float4-vectorized) ----
    #pragma unroll
    for (int r = 0; r < 2; ++r) {
        int cnt4 = sdeg[r] * 4;            // 4 float4 per edge slot
        for (int i = tid; i < cnt4; i += 512) {
            int slot = i >> 2, q = i & 3;
            const float4* src =
                (const float4*)(edges + (((size_t)(r0 + r)) * NN + snbr[r][slot]) * EE);
            ((float4*)&efeat[r][slot][0])[q] = src[q];
        }
    }
    __syncthreads();

    // ---- message aggregation: waves 0-3 -> row 0, waves 4-7 -> row 1 ----
    {
        int r = w >> 2, sub = w & 3;
        int d = sdeg[r];
        const float* hb = hn_in + (size_t)b * NN * MM;
        float acc = 0.0f;
        for (int s = sub; s < d; s += 4) {
            int j = snbr[r][s];
            float term = hb[j * MM + lane];
            #pragma unroll
            for (int k = 0; k < EE; ++k) term += efeat[r][s][k] * we[k];
            acc += fmaxf(term, 0.0f);
        }
        part[w][lane] = acc;
    }
    __syncthreads();
    if ((w & 3) == 0) {
        int r = w >> 2;
        smsg[r][lane] = part[w][lane] + part[w + 1][lane]
                      + part[w + 2][lane] + part[w + 3][lane];
    }
    __syncthreads();

    // ---- GRU gates: wave q<3 -> gi gate q (both rows); q in 3..5 -> gh ----
    if (w < 3) {
        float a0 = bi[w * FF + lane], a1 = a0;
        #pragma unroll 4
        for (int k = 0; k < FF; ++k) {
            float wgt = Wi[k * G3 + w * FF + lane];
            a0 += smsg[0][k] * wgt;
            a1 += smsg[1][k] * wgt;
        }
        gI[0][w][lane] = a0; gI[1][w][lane] = a1;
    } else if (w < 6) {
        int g = w - 3;
        float a0 = bh[g * FF + lane], a1 = a0;
        #pragma unroll 4
        for (int k = 0; k < FF; ++k) {
            float wgt = Wh[k * G3 + g * FF + lane];
            a0 += shold[0][k] * wgt;
            a1 += shold[1][k] * wgt;
        }
        gH[0][g][lane] = a0; gH[1][g][lane] = a1;
    }
    __syncthreads();

    // ---- combine: 128 threads = 2 rows x 64 features ----
    if (tid < 2 * FF) {
        int r = tid >> 6, tt = tid & 63;
        float rr = sigmoidf_(gI[r][0][tt] + gH[r][0][tt]);
        float zz = sigmoidf_(gI[r][1][tt] + gH[r][1][tt]);
        float ng = tanhf(gI[r][2][tt] + rr * gH[r][2][tt]);
        float hold = shold[r][tt];
        float hnew = (1.0f - zz) * ng + zz * hold;
        if (sdeg[r] == 0) hnew = hold;       // node_mask scatter semantics
        shnew[r][tt] = hnew;
        h[(size_t)(r0 + r) * FF + tt] = hnew;
    }
    __syncthreads();

    if (!last) {
        // hn for next pass: h_new @ W_n + b_msg; wave w -> (row w>>2, k-quarter w&3)
        {
            int r = w >> 2, kq = w & 3;
            float p = 0.0f;
            #pragma unroll
            for (int kk = 0; kk < 16; ++kk) {
                int k = kq * 16 + kk;
                p += shnew[r][k] * Wmsg[k * MM + lane];
            }
            part[w][lane] = p;
        }
        __syncthreads();
        if (tid < 2 * MM) {
            int r = tid >> 6, tt = tid & 63;
            hn_out[(size_t)(r0 + r) * MM + tt] = bmsg[tt]
                + part[r*4+0][tt] + part[r*4+1][tt] + part[r*4+2][tt] + part[r*4+3][tt];
        }
    } else {
        // gated readout: 4 groups of 128 thr = (row, gate-vs-emb)
        int grp = tid >> 7, o = tid & 127;
        int r = grp >> 1, kind = grp & 1;
        if (kind == 0) {
            float g = bg[o];
            #pragma unroll 4
            for (int k = 0; k < FF; ++k) g += shnew[r][k] * Wg[k * OUTD + o];
            #pragma unroll 4
            for (int k = 0; k < FF; ++k) g += sx[r][k] * Wg[(FF + k) * OUTD + o];
            sg[r][o] = g;
        } else {
            float e = be[o];
            #pragma unroll 4
            for (int k = 0; k < FF; ++k) e += shnew[r][k] * We[k * OUTD + o];
            se[r][o] = e;
        }
        __syncthreads();
        if (tid < OUTD) {
            float v0 = (sdeg[0] != 0) ? sigmoidf_(sg[0][tid]) * se[0][tid] : 0.0f;
            float v1 = (sdeg[1] != 0) ? sigmoidf_(sg[1][tid]) * se[1][tid] : 0.0f;
            atomicAdd(&out[b * OUTD + tid], v0 + v1);
        }
    }
}

// ---------------------------------------------------------------------------
extern "C" void kernel_launch(void* const* d_in, const int* in_sizes, int n_in,
                              void* d_out, int out_size, void* d_ws, size_t ws_size,
                              hipStream_t stream) {
    const float* nodes = (const float*)d_in[0];
    const float* edges = (const float*)d_in[1];
    const float* Wmsg  = (const float*)d_in[2];
    const float* bmsg  = (const float*)d_in[3];
    const float* Wi    = (const float*)d_in[4];
    const float* Wh    = (const float*)d_in[5];
    const float* bi    = (const float*)d_in[6];
    const float* bh    = (const float*)d_in[7];
    const float* Wg    = (const float*)d_in[8];
    const float* bg    = (const float*)d_in[9];
    const float* We    = (const float*)d_in[10];
    const float* be    = (const float*)d_in[11];
    float* out = (float*)d_out;
    char* ws = (char*)d_ws;

    int*   deg  = (int*)ws;                                   // 8 KB
    int*   nbr  = (int*)(ws + 8192);                          // 512 KB
    float* h    = (float*)(ws + 8192 + (size_t)ROWS * MAXD * 4);
    float* hnA  = h   + (size_t)ROWS * FF;                    // 512 KB
    float* hnB  = hnA + (size_t)ROWS * MM;                    // 512 KB

    k_prep<<<ROWS, 256, 0, stream>>>(nodes, edges, Wmsg, bmsg, deg, nbr, h, hnA, out);

    // pass 0: hnA -> hnB ; pass 1: hnB -> hnA ; pass 2: hnA -> readout
    k_pass2<<<ROWS/2, 512, 0, stream>>>(edges, Wmsg, bmsg, Wi, Wh, bi, bh,
                                        nodes, Wg, bg, We, be, deg, nbr,
                                        hnA, hnB, h, out, 0);
    k_pass2<<<ROWS/2, 512, 0, stream>>>(edges, Wmsg, bmsg, Wi, Wh, bi, bh,
                                        nodes, Wg, bg, We, be, deg, nbr,
                                        hnB, hnA, h, out, 0);
    k_pass2<<<ROWS/2, 512, 0, stream>>>(edges, Wmsg, bmsg, Wi, Wh, bi, bh,
                                        nodes, Wg, bg, We, be, deg, nbr,
                                        hnA, hnB, h, out, 1);
}